// Round 15
// baseline (215.932 us; speedup 1.0000x reference)
//
#include <hip/hip_runtime.h>
#include <hip/hip_bf16.h>

#define TPB 256
#define BSHIFT 7                 // 128 nodes per bucket
#define BNODES (1 << BSHIFT)
#define NWRITERS 256             // edge-chunk writer blocks

typedef int vint4 __attribute__((ext_vector_type(4)));
typedef __attribute__((ext_vector_type(8))) short short8v;   // 8 bf16 (4 VGPRs)
typedef __attribute__((ext_vector_type(4))) float f32x4;

// f32 -> bf16 bits, RNE
__device__ __forceinline__ unsigned short f2bf(float f) {
    unsigned int u = __float_as_uint(f);
    u += 0x7fffu + ((u >> 16) & 1u);
    return (unsigned short)(u >> 16);
}
__device__ __forceinline__ float bflo(unsigned int u) { return __uint_as_float(u << 16); }
__device__ __forceinline__ float bfhi(unsigned int u) { return __uint_as_float(u & 0xffff0000u); }

// ---- K1: fused [hist: per-writer bucket counts] + [gemm1 MFMA: xlb = bf16(x@W1+b1)] ----
__global__ __launch_bounds__(TPB) void k_gemm1_hist(
    const float* __restrict__ x, const float* __restrict__ W1, const float* __restrict__ b1,
    unsigned int* __restrict__ xlb,
    const int* __restrict__ ei, int* __restrict__ cntT,
    int N, int E, int NB, int CH)
{
    __shared__ unsigned short wT[64 * 136];   // W1^T bf16, stride 136 (2-way = free)
    __shared__ float b1s[64];
    __shared__ int   lcnt[1024];

    const int t = threadIdx.x;

    if ((int)blockIdx.x < NWRITERS) {
        const int hb = blockIdx.x;
        const int start = hb * CH;
        const int lim = min(E, start + CH);
        for (int j = t; j < NB; j += TPB) lcnt[j] = 0;
        __syncthreads();
        const int* dst = ei + E;
        int i = start + t * 4;
        for (; i + 3 < lim; i += TPB * 4) {
            vint4 d = __builtin_nontemporal_load(reinterpret_cast<const vint4*>(dst + i));
            atomicAdd(&lcnt[d.x >> BSHIFT], 1);
            atomicAdd(&lcnt[d.y >> BSHIFT], 1);
            atomicAdd(&lcnt[d.z >> BSHIFT], 1);
            atomicAdd(&lcnt[d.w >> BSHIFT], 1);
        }
        for (i = start + ((lim - start) & ~3) + t; i < lim; i += TPB)
            atomicAdd(&lcnt[dst[i] >> BSHIFT], 1);
        __syncthreads();
        for (int j = t; j < NB; j += TPB) cntT[j * NWRITERS + hb] = lcnt[j];
        return;
    }

    // ---- gemm1 MFMA: 4 waves x 16 rows = 64 rows/block ----
    for (int i = t; i < 2048; i += TPB) {
        int k = i >> 4, cw = (i & 15) * 4;
        float4 u = reinterpret_cast<const float4*>(W1)[i];
        wT[(cw + 0) * 136 + k] = f2bf(u.x);
        wT[(cw + 1) * 136 + k] = f2bf(u.y);
        wT[(cw + 2) * 136 + k] = f2bf(u.z);
        wT[(cw + 3) * 136 + k] = f2bf(u.w);
    }
    if (t < 64) b1s[t] = b1[t];
    __syncthreads();

    const int l = t & 63, wid = t >> 6;
    const int cl = l & 15, kg = l >> 4;
    const int rw = ((int)blockIdx.x - NWRITERS) * 64 + wid * 16;
    if (rw >= N) return;
    const int r = rw + cl;

    const float4* xp4 = reinterpret_cast<const float4*>(x) + ((size_t)min(r, N - 1) * 32 + kg * 2);

    f32x4 acc[4] = {};
    #pragma unroll
    for (int kt = 0; kt < 4; ++kt) {
        float4 fA = xp4[kt * 8];
        float4 fB = xp4[kt * 8 + 1];
        short8v a;
        a[0] = (short)f2bf(fA.x); a[1] = (short)f2bf(fA.y);
        a[2] = (short)f2bf(fA.z); a[3] = (short)f2bf(fA.w);
        a[4] = (short)f2bf(fB.x); a[5] = (short)f2bf(fB.y);
        a[6] = (short)f2bf(fB.z); a[7] = (short)f2bf(fB.w);
        #pragma unroll
        for (int ct = 0; ct < 4; ++ct) {
            short8v b = *reinterpret_cast<const short8v*>(
                &wT[(ct * 16 + cl) * 136 + kt * 32 + kg * 8]);
            acc[ct] = __builtin_amdgcn_mfma_f32_16x16x32_bf16(a, b, acc[ct], 0, 0, 0);
        }
    }

    #pragma unroll
    for (int ct = 0; ct < 4; ++ct) {
        #pragma unroll
        for (int reg = 0; reg < 4; ++reg) {
            int row = rw + kg * 4 + reg;
            float v = acc[ct][reg] + b1s[ct * 16 + cl];
            unsigned int m = (unsigned int)f2bf(v);
            unsigned int p = (unsigned int)__shfl_xor((int)m, 1);
            if (!(l & 1) && row < N)
                xlb[(size_t)row * 32 + ct * 8 + (cl >> 1)] = m | (p << 16);
        }
    }
}

// ---- K2: per-bucket scan of writer counts -> segT + totals ----
__global__ __launch_bounds__(TPB) void k_colscan(
    const int* __restrict__ cntT, int* __restrict__ segT, int* __restrict__ totals, int NB)
{
    __shared__ int wsum[4];
    const int r = blockIdx.x;
    const int t = threadIdx.x;
    const int lane = t & 63, wid = t >> 6;
    int v = cntT[r * NWRITERS + t];
    int incl = v;
    for (int d = 1; d < 64; d <<= 1) {
        int n = __shfl_up(incl, d);
        if (lane >= d) incl += n;
    }
    if (lane == 63) wsum[wid] = incl;
    __syncthreads();
    int woff = 0;
    for (int w = 0; w < wid; w++) woff += wsum[w];
    int excl = woff + incl - v;
    segT[r * NWRITERS + t] = excl;
    if (t == TPB - 1) totals[r] = excl + v;
}

// ---- K3: bin edges into block-private (writer,bucket) segments ----
__global__ __launch_bounds__(TPB) void k_fillbin(
    const int* __restrict__ ei, const int* __restrict__ segT, const int* __restrict__ totals,
    unsigned int* __restrict__ recs, int E, int NB, int CH)
{
    __shared__ int lcur[1024];
    __shared__ int bbs[1024];
    __shared__ int wsum[4];
    const int blk = blockIdx.x;
    const int t = threadIdx.x;
    const int lane = t & 63, wid = t >> 6;

    // exclusive scan of totals[0..NB-1] -> bbs (4 elems/thread)
    const int b4 = t * 4;
    int v0 = (b4 + 0 < NB) ? totals[b4 + 0] : 0;
    int v1 = (b4 + 1 < NB) ? totals[b4 + 1] : 0;
    int v2 = (b4 + 2 < NB) ? totals[b4 + 2] : 0;
    int v3 = (b4 + 3 < NB) ? totals[b4 + 3] : 0;
    int tsum = v0 + v1 + v2 + v3;
    int incl = tsum;
    for (int d = 1; d < 64; d <<= 1) {
        int n = __shfl_up(incl, d);
        if (lane >= d) incl += n;
    }
    if (lane == 63) wsum[wid] = incl;
    __syncthreads();
    int woff = 0;
    for (int w = 0; w < wid; w++) woff += wsum[w];
    int texcl = woff + incl - tsum;
    if (b4 + 0 < NB) bbs[b4 + 0] = texcl;
    if (b4 + 1 < NB) bbs[b4 + 1] = texcl + v0;
    if (b4 + 2 < NB) bbs[b4 + 2] = texcl + v0 + v1;
    if (b4 + 3 < NB) bbs[b4 + 3] = texcl + v0 + v1 + v2;
    __syncthreads();

    for (int j = t; j < NB; j += TPB)
        lcur[j] = bbs[j] + segT[j * NWRITERS + blk];
    __syncthreads();

    const int start = blk * CH;
    const int lim = min(E, start + CH);
    const int* src = ei;
    const int* dst = ei + E;
    int i = start + t * 4;
    for (; i + 3 < lim; i += TPB * 4) {
        vint4 d = __builtin_nontemporal_load(reinterpret_cast<const vint4*>(dst + i));
        vint4 s = __builtin_nontemporal_load(reinterpret_cast<const vint4*>(src + i));
        int p0 = atomicAdd(&lcur[d.x >> BSHIFT], 1);
        int p1 = atomicAdd(&lcur[d.y >> BSHIFT], 1);
        int p2 = atomicAdd(&lcur[d.z >> BSHIFT], 1);
        int p3 = atomicAdd(&lcur[d.w >> BSHIFT], 1);
        recs[p0] = ((unsigned int)s.x << BSHIFT) | (unsigned int)(d.x & (BNODES-1));
        recs[p1] = ((unsigned int)s.y << BSHIFT) | (unsigned int)(d.y & (BNODES-1));
        recs[p2] = ((unsigned int)s.z << BSHIFT) | (unsigned int)(d.z & (BNODES-1));
        recs[p3] = ((unsigned int)s.w << BSHIFT) | (unsigned int)(d.w & (BNODES-1));
    }
    for (i = start + ((lim - start) & ~3) + t; i < lim; i += TPB) {
        int d = dst[i];
        int p = atomicAdd(&lcur[d >> BSHIFT], 1);
        recs[p] = ((unsigned int)src[i] << BSHIFT) | (unsigned int)(d & (BNODES-1));
    }
}

// ---- K4: per-bucket counting sort -> node-sorted esrc + global off ----
__global__ __launch_bounds__(TPB) void k_bsort(
    const unsigned int* __restrict__ recs, const int* __restrict__ totals,
    int* __restrict__ esrc, int* __restrict__ off, int N, int NB, int E)
{
    __shared__ int h[BNODES];
    __shared__ int cur[BNODES];
    __shared__ int ws2[2];
    __shared__ int red[4];

    const int r = blockIdx.x;
    const int t = threadIdx.x;
    const int lane = t & 63, w = t >> 6;

    int s = 0;
    for (int j = t; j < r; j += TPB) s += totals[j];
    #pragma unroll
    for (int d = 32; d >= 1; d >>= 1) s += __shfl_xor(s, d);
    if (lane == 0) red[w] = s;
    if (t < BNODES) h[t] = 0;
    __syncthreads();
    const int bb0 = red[0] + red[1] + red[2] + red[3];
    const int bb1 = bb0 + totals[r];

    for (int i = bb0 + t; i < bb1; i += TPB)
        atomicAdd(&h[recs[i] & (BNODES - 1)], 1);
    __syncthreads();

    int v = 0, incl = 0;
    if (t < BNODES) {
        v = h[t];
        incl = v;
        for (int d = 1; d < 64; d <<= 1) {
            int n = __shfl_up(incl, d);
            if (lane >= d) incl += n;
        }
        if (lane == 63) ws2[w] = incl;
    }
    __syncthreads();
    if (t < BNODES) {
        int excl = incl - v + (w ? ws2[0] : 0);
        cur[t] = bb0 + excl;
        int node = r * BNODES + t;
        if (node < N) off[node] = bb0 + excl;
    }
    if (r == NB - 1 && t == 0) off[N] = E;
    __syncthreads();

    for (int i = bb0 + t; i < bb1; i += TPB) {
        unsigned int rec = recs[i];
        int p = atomicAdd(&cur[rec & (BNODES - 1)], 1);
        esrc[p] = (int)(rec >> BSHIFT);
    }
}

// ---- K5: lockstep sequential-quarter aggregation + self-loop + ReLU ----
// ALL blocks process quarter 0, then 1,2,3 (outer loop). Grid = 2048 blocks
// = exactly resident at launch (8 blocks/CU) -> blocks start each quarter
// nearly together; during a quarter-pass every XCD's L2 caches the SAME
// 3.2 MB xlb slice (fits 4 MB) regardless of block->XCD mapping.
// esrc reads are nontemporal so the stream doesn't evict the hot slice.
// aggq stored QUARTER-MAJOR: each pass writes a contiguous 3.2 MB region.
#define AGG2_BLOCKS 2048
__global__ __launch_bounds__(TPB) void k_aggq2(
    const unsigned int* __restrict__ xlb,  // [N,32] u32 (bf16 pairs)
    const int* __restrict__ off,           // [N+1]
    const int* __restrict__ esrc,          // [E]
    unsigned int* __restrict__ aggq,       // [4][N,8] u32, quarter-major, relu'd
    int N)
{
    const int t = threadIdx.x;
    const int wid = t >> 6, lane = t & 63;
    const int sl = lane >> 2, fl = lane & 3;      // 16 edge slots x 4 feature-lanes
    const uint2* xb2 = reinterpret_cast<const uint2*>(xlb);

    for (int q = 0; q < 4; ++q) {
        uint2* aq = reinterpret_cast<uint2*>(aggq + (size_t)q * N * 8);
        const int qoff = q * 4 + fl;
        for (int node = blockIdx.x * 4 + wid; node < N; node += AGG2_BLOCKS * 4) {
            const int beg = off[node], end = off[node + 1];
            float a0 = 0.f, a1 = 0.f, a2 = 0.f, a3 = 0.f;
            int e = beg + sl;
            for (; e + 16 < end; e += 32) {       // 2-deep unroll
                int s0 = __builtin_nontemporal_load(esrc + e);
                int s1 = __builtin_nontemporal_load(esrc + e + 16);
                uint2 v0 = xb2[(size_t)s0 * 16 + qoff];
                uint2 v1 = xb2[(size_t)s1 * 16 + qoff];
                a0 += bflo(v0.x); a1 += bfhi(v0.x); a2 += bflo(v0.y); a3 += bfhi(v0.y);
                a0 += bflo(v1.x); a1 += bfhi(v1.x); a2 += bflo(v1.y); a3 += bfhi(v1.y);
            }
            if (e < end) {
                int s = __builtin_nontemporal_load(esrc + e);
                uint2 v = xb2[(size_t)s * 16 + qoff];
                a0 += bflo(v.x); a1 += bfhi(v.x); a2 += bflo(v.y); a3 += bfhi(v.y);
            }
            // reduce across 16 slots (lane bits 2..5)
            #pragma unroll
            for (int d = 4; d <= 32; d <<= 1) {
                a0 += __shfl_xor(a0, d); a1 += __shfl_xor(a1, d);
                a2 += __shfl_xor(a2, d); a3 += __shfl_xor(a3, d);
            }
            if (sl == 0) {
                uint2 sv = xb2[(size_t)node * 16 + qoff];   // self-loop
                float r0 = fmaxf(a0 + bflo(sv.x), 0.f);
                float r1 = fmaxf(a1 + bfhi(sv.x), 0.f);
                float r2 = fmaxf(a2 + bflo(sv.y), 0.f);
                float r3 = fmaxf(a3 + bfhi(sv.y), 0.f);
                uint2 pk;
                pk.x = (unsigned int)f2bf(r0) | ((unsigned int)f2bf(r1) << 16);
                pk.y = (unsigned int)f2bf(r2) | ((unsigned int)f2bf(r3) << 16);
                aq[(size_t)node * 4 + fl] = pk;
            }
        }
    }
}

// ---- K6: out = relu'd-agg @ W2 + b2, reading 4 quarter-major slices ----
__global__ __launch_bounds__(TPB) void k_gemm2b(
    const unsigned int* __restrict__ aggq,  // [4][N,8] u32
    const float* __restrict__ W2,           // [64,32]
    const float* __restrict__ b2,           // [32]
    float* __restrict__ out, int N)
{
    __shared__ float w2s[64 * 32];   // 8 KB
    __shared__ float as[64 * 68];    // stride 68 (2-way = free)
    __shared__ float b2s[32];

    const int t = threadIdx.x;
    const int rbase = blockIdx.x * 64;
    const int rows = min(64, N - rbase);

    const float4* w4 = reinterpret_cast<const float4*>(W2);
    for (int i = t; i < 512; i += TPB) {
        float4 u = w4[i];
        int o = i * 4;
        w2s[o+0] = u.x; w2s[o+1] = u.y; w2s[o+2] = u.z; w2s[o+3] = u.w;
    }
    if (t < 32) b2s[t] = b2[t];

    // stage: per quarter q, rows*2 uint4 (8 feats each), coalesced
    #pragma unroll
    for (int q = 0; q < 4; ++q) {
        const uint4* a4 = reinterpret_cast<const uint4*>(aggq + (size_t)q * N * 8 + (size_t)rbase * 8);
        for (int i = t; i < rows * 2; i += TPB) {
            uint4 v = a4[i];
            int row = i >> 1, half = i & 1;
            float* p = &as[row * 68 + q * 16 + half * 8];
            p[0] = bflo(v.x); p[1] = bfhi(v.x);
            p[2] = bflo(v.y); p[3] = bfhi(v.y);
            p[4] = bflo(v.z); p[5] = bfhi(v.z);
            p[6] = bflo(v.w); p[7] = bfhi(v.w);
        }
    }
    __syncthreads();

    const int row = t >> 2, cg = t & 3;   // 4 threads/row, 8 cols each
    if (row < rows) {
        float acc[8];
        #pragma unroll
        for (int c = 0; c < 8; c++) acc[c] = b2s[cg*8 + c];
        const float* ar = &as[row * 68];
        #pragma unroll 4
        for (int k = 0; k < 64; k++) {
            float a = ar[k];
            const float* wp = &w2s[k*32 + cg*8];
            #pragma unroll
            for (int c = 0; c < 8; c++) acc[c] = fmaf(a, wp[c], acc[c]);
        }
        float4* op = reinterpret_cast<float4*>(out + (size_t)(rbase + row) * 32 + cg * 8);
        op[0] = make_float4(acc[0], acc[1], acc[2], acc[3]);
        op[1] = make_float4(acc[4], acc[5], acc[6], acc[7]);
    }
}

extern "C" void kernel_launch(void* const* d_in, const int* in_sizes, int n_in,
                              void* d_out, int out_size, void* d_ws, size_t ws_size,
                              hipStream_t stream) {
    const float* x  = (const float*)d_in[0];
    const int*   ei = (const int*)d_in[1];
    const float* W1 = (const float*)d_in[2];
    const float* b1 = (const float*)d_in[3];
    const float* W2 = (const float*)d_in[4];
    const float* b2 = (const float*)d_in[5];
    float* out = (float*)d_out;

    const int N = in_sizes[0] / 128;
    const int E = in_sizes[1] / 2;
    const int NB = (N + BNODES - 1) >> BSHIFT;
    const int CH = (((E + NWRITERS - 1) / NWRITERS) + 3) & ~3;

    char* w = (char*)d_ws;
    unsigned int* xlb  = (unsigned int*)w;  w += (size_t)N * 32 * 4;          // 12.8 MB
    unsigned int* aggq = (unsigned int*)w;  w += (size_t)N * 32 * 4;          // 12.8 MB (4 x N x 8)
    int* cntT   = (int*)w;                  w += (size_t)NB * NWRITERS * 4;   // 800 KB
    int* segT   = (int*)w;                  w += (size_t)NB * NWRITERS * 4;   // 800 KB
    int* totals = (int*)w;                  w += ((size_t)NB * 4 + 15) & ~15ull;
    int* off    = (int*)w;                  w += ((size_t)(N + 1) * 4 + 15) & ~15ull;
    unsigned int* recs = (unsigned int*)w;  w += (size_t)E * 4;               // 6.4 MB
    int* esrc   = (int*)w;                  // 6.4 MB

    const int nbG = (N + 63) / 64;

    hipLaunchKernelGGL(k_gemm1_hist, dim3(NWRITERS + nbG), dim3(TPB), 0, stream,
                       x, W1, b1, xlb, ei, cntT, N, E, NB, CH);
    hipLaunchKernelGGL(k_colscan, dim3(NB), dim3(TPB), 0, stream, cntT, segT, totals, NB);
    hipLaunchKernelGGL(k_fillbin, dim3(NWRITERS), dim3(TPB), 0, stream,
                       ei, segT, totals, recs, E, NB, CH);
    hipLaunchKernelGGL(k_bsort, dim3(NB), dim3(TPB), 0, stream,
                       recs, totals, esrc, off, N, NB, E);
    hipLaunchKernelGGL(k_aggq2, dim3(AGG2_BLOCKS), dim3(TPB), 0, stream,
                       xlb, off, esrc, aggq, N);
    hipLaunchKernelGGL(k_gemm2b, dim3(nbG), dim3(TPB), 0, stream,
                       aggq, W2, b2, out, N);
}

// Round 16
// 203.018 us; speedup vs baseline: 1.0636x; 1.0636x over previous
//
#include <hip/hip_runtime.h>
#include <hip/hip_bf16.h>

#define TPB 256
#define BSHIFT 7                 // 128 nodes per bucket
#define BNODES (1 << BSHIFT)
#define NWRITERS 256             // edge-chunk writer blocks

typedef int vint4 __attribute__((ext_vector_type(4)));
typedef __attribute__((ext_vector_type(8))) short short8v;   // 8 bf16 (4 VGPRs)
typedef __attribute__((ext_vector_type(4))) float f32x4;

// f32 -> bf16 bits, RNE
__device__ __forceinline__ unsigned short f2bf(float f) {
    unsigned int u = __float_as_uint(f);
    u += 0x7fffu + ((u >> 16) & 1u);
    return (unsigned short)(u >> 16);
}
__device__ __forceinline__ float bflo(unsigned int u) { return __uint_as_float(u << 16); }
__device__ __forceinline__ float bfhi(unsigned int u) { return __uint_as_float(u & 0xffff0000u); }

// ---- K1: fused [hist] + [gemm1 MFMA -> xlq QUARTER-MAJOR [4][N][8 u32]] ----
// Quarter-major is the key: quarter q of all nodes is a CONTIGUOUS 3.2 MB
// region -> fits one XCD's 4 MB L2 during the aggregation quarter-pass.
// (Row-major slicing failed: 128 B lines made every pass touch all 12.8 MB.)
__global__ __launch_bounds__(TPB) void k_gemm1_hist(
    const float* __restrict__ x, const float* __restrict__ W1, const float* __restrict__ b1,
    unsigned int* __restrict__ xlq,
    const int* __restrict__ ei, int* __restrict__ cntT,
    int N, int E, int NB, int CH)
{
    __shared__ unsigned short wT[64 * 136];   // W1^T bf16, stride 136 (2-way = free)
    __shared__ float b1s[64];
    __shared__ int   lcnt[1024];

    const int t = threadIdx.x;

    if ((int)blockIdx.x < NWRITERS) {
        const int hb = blockIdx.x;
        const int start = hb * CH;
        const int lim = min(E, start + CH);
        for (int j = t; j < NB; j += TPB) lcnt[j] = 0;
        __syncthreads();
        const int* dst = ei + E;
        int i = start + t * 4;
        for (; i + 3 < lim; i += TPB * 4) {
            vint4 d = __builtin_nontemporal_load(reinterpret_cast<const vint4*>(dst + i));
            atomicAdd(&lcnt[d.x >> BSHIFT], 1);
            atomicAdd(&lcnt[d.y >> BSHIFT], 1);
            atomicAdd(&lcnt[d.z >> BSHIFT], 1);
            atomicAdd(&lcnt[d.w >> BSHIFT], 1);
        }
        for (i = start + ((lim - start) & ~3) + t; i < lim; i += TPB)
            atomicAdd(&lcnt[dst[i] >> BSHIFT], 1);
        __syncthreads();
        for (int j = t; j < NB; j += TPB) cntT[j * NWRITERS + hb] = lcnt[j];
        return;
    }

    // ---- gemm1 MFMA: 4 waves x 16 rows = 64 rows/block ----
    for (int i = t; i < 2048; i += TPB) {
        int k = i >> 4, cw = (i & 15) * 4;
        float4 u = reinterpret_cast<const float4*>(W1)[i];
        wT[(cw + 0) * 136 + k] = f2bf(u.x);
        wT[(cw + 1) * 136 + k] = f2bf(u.y);
        wT[(cw + 2) * 136 + k] = f2bf(u.z);
        wT[(cw + 3) * 136 + k] = f2bf(u.w);
    }
    if (t < 64) b1s[t] = b1[t];
    __syncthreads();

    const int l = t & 63, wid = t >> 6;
    const int cl = l & 15, kg = l >> 4;
    const int rw = ((int)blockIdx.x - NWRITERS) * 64 + wid * 16;
    if (rw >= N) return;
    const int r = rw + cl;

    const float4* xp4 = reinterpret_cast<const float4*>(x) + ((size_t)min(r, N - 1) * 32 + kg * 2);

    f32x4 acc[4] = {};
    #pragma unroll
    for (int kt = 0; kt < 4; ++kt) {
        float4 fA = xp4[kt * 8];
        float4 fB = xp4[kt * 8 + 1];
        short8v a;
        a[0] = (short)f2bf(fA.x); a[1] = (short)f2bf(fA.y);
        a[2] = (short)f2bf(fA.z); a[3] = (short)f2bf(fA.w);
        a[4] = (short)f2bf(fB.x); a[5] = (short)f2bf(fB.y);
        a[6] = (short)f2bf(fB.z); a[7] = (short)f2bf(fB.w);
        #pragma unroll
        for (int ct = 0; ct < 4; ++ct) {
            short8v b = *reinterpret_cast<const short8v*>(
                &wT[(ct * 16 + cl) * 136 + kt * 32 + kg * 8]);
            acc[ct] = __builtin_amdgcn_mfma_f32_16x16x32_bf16(a, b, acc[ct], 0, 0, 0);
        }
    }

    // C store, QUARTER-MAJOR: quarter ct at xlq[ct*N*8 + row*8 + word]
    #pragma unroll
    for (int ct = 0; ct < 4; ++ct) {
        #pragma unroll
        for (int reg = 0; reg < 4; ++reg) {
            int row = rw + kg * 4 + reg;
            float v = acc[ct][reg] + b1s[ct * 16 + cl];
            unsigned int m = (unsigned int)f2bf(v);
            unsigned int p = (unsigned int)__shfl_xor((int)m, 1);
            if (!(l & 1) && row < N)
                xlq[(size_t)ct * N * 8 + (size_t)row * 8 + (cl >> 1)] = m | (p << 16);
        }
    }
}

// ---- K2: per-bucket scan of writer counts -> segT + totals ----
__global__ __launch_bounds__(TPB) void k_colscan(
    const int* __restrict__ cntT, int* __restrict__ segT, int* __restrict__ totals, int NB)
{
    __shared__ int wsum[4];
    const int r = blockIdx.x;
    const int t = threadIdx.x;
    const int lane = t & 63, wid = t >> 6;
    int v = cntT[r * NWRITERS + t];
    int incl = v;
    for (int d = 1; d < 64; d <<= 1) {
        int n = __shfl_up(incl, d);
        if (lane >= d) incl += n;
    }
    if (lane == 63) wsum[wid] = incl;
    __syncthreads();
    int woff = 0;
    for (int w = 0; w < wid; w++) woff += wsum[w];
    int excl = woff + incl - v;
    segT[r * NWRITERS + t] = excl;
    if (t == TPB - 1) totals[r] = excl + v;
}

// ---- K3: bin edges into block-private (writer,bucket) segments ----
__global__ __launch_bounds__(TPB) void k_fillbin(
    const int* __restrict__ ei, const int* __restrict__ segT, const int* __restrict__ totals,
    unsigned int* __restrict__ recs, int E, int NB, int CH)
{
    __shared__ int lcur[1024];
    __shared__ int bbs[1024];
    __shared__ int wsum[4];
    const int blk = blockIdx.x;
    const int t = threadIdx.x;
    const int lane = t & 63, wid = t >> 6;

    const int b4 = t * 4;
    int v0 = (b4 + 0 < NB) ? totals[b4 + 0] : 0;
    int v1 = (b4 + 1 < NB) ? totals[b4 + 1] : 0;
    int v2 = (b4 + 2 < NB) ? totals[b4 + 2] : 0;
    int v3 = (b4 + 3 < NB) ? totals[b4 + 3] : 0;
    int tsum = v0 + v1 + v2 + v3;
    int incl = tsum;
    for (int d = 1; d < 64; d <<= 1) {
        int n = __shfl_up(incl, d);
        if (lane >= d) incl += n;
    }
    if (lane == 63) wsum[wid] = incl;
    __syncthreads();
    int woff = 0;
    for (int w = 0; w < wid; w++) woff += wsum[w];
    int texcl = woff + incl - tsum;
    if (b4 + 0 < NB) bbs[b4 + 0] = texcl;
    if (b4 + 1 < NB) bbs[b4 + 1] = texcl + v0;
    if (b4 + 2 < NB) bbs[b4 + 2] = texcl + v0 + v1;
    if (b4 + 3 < NB) bbs[b4 + 3] = texcl + v0 + v1 + v2;
    __syncthreads();

    for (int j = t; j < NB; j += TPB)
        lcur[j] = bbs[j] + segT[j * NWRITERS + blk];
    __syncthreads();

    const int start = blk * CH;
    const int lim = min(E, start + CH);
    const int* src = ei;
    const int* dst = ei + E;
    int i = start + t * 4;
    for (; i + 3 < lim; i += TPB * 4) {
        vint4 d = __builtin_nontemporal_load(reinterpret_cast<const vint4*>(dst + i));
        vint4 s = __builtin_nontemporal_load(reinterpret_cast<const vint4*>(src + i));
        int p0 = atomicAdd(&lcur[d.x >> BSHIFT], 1);
        int p1 = atomicAdd(&lcur[d.y >> BSHIFT], 1);
        int p2 = atomicAdd(&lcur[d.z >> BSHIFT], 1);
        int p3 = atomicAdd(&lcur[d.w >> BSHIFT], 1);
        recs[p0] = ((unsigned int)s.x << BSHIFT) | (unsigned int)(d.x & (BNODES-1));
        recs[p1] = ((unsigned int)s.y << BSHIFT) | (unsigned int)(d.y & (BNODES-1));
        recs[p2] = ((unsigned int)s.z << BSHIFT) | (unsigned int)(d.z & (BNODES-1));
        recs[p3] = ((unsigned int)s.w << BSHIFT) | (unsigned int)(d.w & (BNODES-1));
    }
    for (i = start + ((lim - start) & ~3) + t; i < lim; i += TPB) {
        int d = dst[i];
        int p = atomicAdd(&lcur[d >> BSHIFT], 1);
        recs[p] = ((unsigned int)src[i] << BSHIFT) | (unsigned int)(d & (BNODES-1));
    }
}

// ---- K4: per-bucket counting sort -> node-sorted esrc + global off ----
__global__ __launch_bounds__(TPB) void k_bsort(
    const unsigned int* __restrict__ recs, const int* __restrict__ totals,
    int* __restrict__ esrc, int* __restrict__ off, int N, int NB, int E)
{
    __shared__ int h[BNODES];
    __shared__ int cur[BNODES];
    __shared__ int ws2[2];
    __shared__ int red[4];

    const int r = blockIdx.x;
    const int t = threadIdx.x;
    const int lane = t & 63, w = t >> 6;

    int s = 0;
    for (int j = t; j < r; j += TPB) s += totals[j];
    #pragma unroll
    for (int d = 32; d >= 1; d >>= 1) s += __shfl_xor(s, d);
    if (lane == 0) red[w] = s;
    if (t < BNODES) h[t] = 0;
    __syncthreads();
    const int bb0 = red[0] + red[1] + red[2] + red[3];
    const int bb1 = bb0 + totals[r];

    for (int i = bb0 + t; i < bb1; i += TPB)
        atomicAdd(&h[recs[i] & (BNODES - 1)], 1);
    __syncthreads();

    int v = 0, incl = 0;
    if (t < BNODES) {
        v = h[t];
        incl = v;
        for (int d = 1; d < 64; d <<= 1) {
            int n = __shfl_up(incl, d);
            if (lane >= d) incl += n;
        }
        if (lane == 63) ws2[w] = incl;
    }
    __syncthreads();
    if (t < BNODES) {
        int excl = incl - v + (w ? ws2[0] : 0);
        cur[t] = bb0 + excl;
        int node = r * BNODES + t;
        if (node < N) off[node] = bb0 + excl;
    }
    if (r == NB - 1 && t == 0) off[N] = E;
    __syncthreads();

    for (int i = bb0 + t; i < bb1; i += TPB) {
        unsigned int rec = recs[i];
        int p = atomicAdd(&cur[rec & (BNODES - 1)], 1);
        esrc[p] = (int)(rec >> BSHIFT);
    }
}

// ---- K5: lockstep quarter-pass aggregation over QUARTER-MAJOR xlq ----
// All 2048 resident blocks sweep quarter 0..3; during a pass the gather
// working set is the contiguous 3.2 MB slice -> L2-resident per XCD.
#define AGG2_BLOCKS 2048
__global__ __launch_bounds__(TPB) void k_aggq2(
    const unsigned int* __restrict__ xlq,  // [4][N][8] u32 (bf16 pairs)
    const int* __restrict__ off,           // [N+1]
    const int* __restrict__ esrc,          // [E]
    unsigned int* __restrict__ aggq,       // [4][N][8] u32, relu'd
    int N)
{
    const int t = threadIdx.x;
    const int wid = t >> 6, lane = t & 63;
    const int sl = lane >> 2, fl = lane & 3;      // 16 edge slots x 4 feature-lanes

    for (int q = 0; q < 4; ++q) {
        const uint2* xq = reinterpret_cast<const uint2*>(xlq + (size_t)q * N * 8);
        uint2* aq = reinterpret_cast<uint2*>(aggq + (size_t)q * N * 8);
        for (int node = blockIdx.x * 4 + wid; node < N; node += AGG2_BLOCKS * 4) {
            const int beg = off[node], end = off[node + 1];
            float a0 = 0.f, a1 = 0.f, a2 = 0.f, a3 = 0.f;
            int e = beg + sl;
            for (; e + 16 < end; e += 32) {       // 2-deep unroll
                int s0 = __builtin_nontemporal_load(esrc + e);
                int s1 = __builtin_nontemporal_load(esrc + e + 16);
                uint2 v0 = xq[(size_t)s0 * 4 + fl];
                uint2 v1 = xq[(size_t)s1 * 4 + fl];
                a0 += bflo(v0.x); a1 += bfhi(v0.x); a2 += bflo(v0.y); a3 += bfhi(v0.y);
                a0 += bflo(v1.x); a1 += bfhi(v1.x); a2 += bflo(v1.y); a3 += bfhi(v1.y);
            }
            if (e < end) {
                int s = __builtin_nontemporal_load(esrc + e);
                uint2 v = xq[(size_t)s * 4 + fl];
                a0 += bflo(v.x); a1 += bfhi(v.x); a2 += bflo(v.y); a3 += bfhi(v.y);
            }
            #pragma unroll
            for (int d = 4; d <= 32; d <<= 1) {
                a0 += __shfl_xor(a0, d); a1 += __shfl_xor(a1, d);
                a2 += __shfl_xor(a2, d); a3 += __shfl_xor(a3, d);
            }
            if (sl == 0) {
                uint2 sv = xq[(size_t)node * 4 + fl];   // self-loop
                float r0 = fmaxf(a0 + bflo(sv.x), 0.f);
                float r1 = fmaxf(a1 + bfhi(sv.x), 0.f);
                float r2 = fmaxf(a2 + bflo(sv.y), 0.f);
                float r3 = fmaxf(a3 + bfhi(sv.y), 0.f);
                uint2 pk;
                pk.x = (unsigned int)f2bf(r0) | ((unsigned int)f2bf(r1) << 16);
                pk.y = (unsigned int)f2bf(r2) | ((unsigned int)f2bf(r3) << 16);
                aq[(size_t)node * 4 + fl] = pk;
            }
        }
    }
}

// ---- K6: out = relu'd-agg @ W2 + b2, reading 4 quarter-major slices ----
__global__ __launch_bounds__(TPB) void k_gemm2b(
    const unsigned int* __restrict__ aggq,  // [4][N][8] u32
    const float* __restrict__ W2,           // [64,32]
    const float* __restrict__ b2,           // [32]
    float* __restrict__ out, int N)
{
    __shared__ float w2s[64 * 32];   // 8 KB
    __shared__ float as[64 * 68];    // stride 68 (2-way = free)
    __shared__ float b2s[32];

    const int t = threadIdx.x;
    const int rbase = blockIdx.x * 64;
    const int rows = min(64, N - rbase);

    const float4* w4 = reinterpret_cast<const float4*>(W2);
    for (int i = t; i < 512; i += TPB) {
        float4 u = w4[i];
        int o = i * 4;
        w2s[o+0] = u.x; w2s[o+1] = u.y; w2s[o+2] = u.z; w2s[o+3] = u.w;
    }
    if (t < 32) b2s[t] = b2[t];

    #pragma unroll
    for (int q = 0; q < 4; ++q) {
        const uint4* a4 = reinterpret_cast<const uint4*>(aggq + (size_t)q * N * 8 + (size_t)rbase * 8);
        for (int i = t; i < rows * 2; i += TPB) {
            uint4 v = a4[i];
            int row = i >> 1, half = i & 1;
            float* p = &as[row * 68 + q * 16 + half * 8];
            p[0] = bflo(v.x); p[1] = bfhi(v.x);
            p[2] = bflo(v.y); p[3] = bfhi(v.y);
            p[4] = bflo(v.z); p[5] = bfhi(v.z);
            p[6] = bflo(v.w); p[7] = bfhi(v.w);
        }
    }
    __syncthreads();

    const int row = t >> 2, cg = t & 3;   // 4 threads/row, 8 cols each
    if (row < rows) {
        float acc[8];
        #pragma unroll
        for (int c = 0; c < 8; c++) acc[c] = b2s[cg*8 + c];
        const float* ar = &as[row * 68];
        #pragma unroll 4
        for (int k = 0; k < 64; k++) {
            float a = ar[k];
            const float* wp = &w2s[k*32 + cg*8];
            #pragma unroll
            for (int c = 0; c < 8; c++) acc[c] = fmaf(a, wp[c], acc[c]);
        }
        float4* op = reinterpret_cast<float4*>(out + (size_t)(rbase + row) * 32 + cg * 8);
        op[0] = make_float4(acc[0], acc[1], acc[2], acc[3]);
        op[1] = make_float4(acc[4], acc[5], acc[6], acc[7]);
    }
}

extern "C" void kernel_launch(void* const* d_in, const int* in_sizes, int n_in,
                              void* d_out, int out_size, void* d_ws, size_t ws_size,
                              hipStream_t stream) {
    const float* x  = (const float*)d_in[0];
    const int*   ei = (const int*)d_in[1];
    const float* W1 = (const float*)d_in[2];
    const float* b1 = (const float*)d_in[3];
    const float* W2 = (const float*)d_in[4];
    const float* b2 = (const float*)d_in[5];
    float* out = (float*)d_out;

    const int N = in_sizes[0] / 128;
    const int E = in_sizes[1] / 2;
    const int NB = (N + BNODES - 1) >> BSHIFT;
    const int CH = (((E + NWRITERS - 1) / NWRITERS) + 3) & ~3;

    char* w = (char*)d_ws;
    unsigned int* xlq  = (unsigned int*)w;  w += (size_t)N * 32 * 4;          // 12.8 MB
    unsigned int* aggq = (unsigned int*)w;  w += (size_t)N * 32 * 4;          // 12.8 MB
    int* cntT   = (int*)w;                  w += (size_t)NB * NWRITERS * 4;   // 800 KB
    int* segT   = (int*)w;                  w += (size_t)NB * NWRITERS * 4;   // 800 KB
    int* totals = (int*)w;                  w += ((size_t)NB * 4 + 15) & ~15ull;
    int* off    = (int*)w;                  w += ((size_t)(N + 1) * 4 + 15) & ~15ull;
    unsigned int* recs = (unsigned int*)w;  w += (size_t)E * 4;               // 6.4 MB
    int* esrc   = (int*)w;                  // 6.4 MB

    const int nbG = (N + 63) / 64;

    hipLaunchKernelGGL(k_gemm1_hist, dim3(NWRITERS + nbG), dim3(TPB), 0, stream,
                       x, W1, b1, xlq, ei, cntT, N, E, NB, CH);
    hipLaunchKernelGGL(k_colscan, dim3(NB), dim3(TPB), 0, stream, cntT, segT, totals, NB);
    hipLaunchKernelGGL(k_fillbin, dim3(NWRITERS), dim3(TPB), 0, stream,
                       ei, segT, totals, recs, E, NB, CH);
    hipLaunchKernelGGL(k_bsort, dim3(NB), dim3(TPB), 0, stream,
                       recs, totals, esrc, off, N, NB, E);
    hipLaunchKernelGGL(k_aggq2, dim3(AGG2_BLOCKS), dim3(TPB), 0, stream,
                       xlq, off, esrc, aggq, N);
    hipLaunchKernelGGL(k_gemm2b, dim3(nbG), dim3(TPB), 0, stream,
                       aggq, W2, b2, out, N);
}

// Round 17
// 124.605 us; speedup vs baseline: 1.7329x; 1.6293x over previous
//
#include <hip/hip_runtime.h>
#include <hip/hip_bf16.h>

#define TPB 256
#define BSHIFT 7                 // 128 nodes per bucket
#define BNODES (1 << BSHIFT)
#define NWRITERS 256             // edge-chunk writer blocks

typedef int vint4 __attribute__((ext_vector_type(4)));
typedef __attribute__((ext_vector_type(8))) short short8v;   // 8 bf16 (4 VGPRs)
typedef __attribute__((ext_vector_type(4))) float f32x4;

// f32 -> bf16 bits, RNE
__device__ __forceinline__ unsigned short f2bf(float f) {
    unsigned int u = __float_as_uint(f);
    u += 0x7fffu + ((u >> 16) & 1u);
    return (unsigned short)(u >> 16);
}
__device__ __forceinline__ float bflo(unsigned int u) { return __uint_as_float(u << 16); }
__device__ __forceinline__ float bfhi(unsigned int u) { return __uint_as_float(u & 0xffff0000u); }

// ---- K1: fused [hist: per-writer bucket counts] + [gemm1 MFMA: xlb = bf16(x@W1+b1)] ----
__global__ __launch_bounds__(TPB) void k_gemm1_hist(
    const float* __restrict__ x, const float* __restrict__ W1, const float* __restrict__ b1,
    unsigned int* __restrict__ xlb,
    const int* __restrict__ ei, int* __restrict__ cntT,
    int N, int E, int NB, int CH)
{
    __shared__ unsigned short wT[64 * 136];   // W1^T bf16, stride 136 (2-way = free)
    __shared__ float b1s[64];
    __shared__ int   lcnt[1024];

    const int t = threadIdx.x;

    if ((int)blockIdx.x < NWRITERS) {
        const int hb = blockIdx.x;
        const int start = hb * CH;
        const int lim = min(E, start + CH);
        for (int j = t; j < NB; j += TPB) lcnt[j] = 0;
        __syncthreads();
        const int* dst = ei + E;
        int i = start + t * 4;
        for (; i + 3 < lim; i += TPB * 4) {
            vint4 d = __builtin_nontemporal_load(reinterpret_cast<const vint4*>(dst + i));
            atomicAdd(&lcnt[d.x >> BSHIFT], 1);
            atomicAdd(&lcnt[d.y >> BSHIFT], 1);
            atomicAdd(&lcnt[d.z >> BSHIFT], 1);
            atomicAdd(&lcnt[d.w >> BSHIFT], 1);
        }
        for (i = start + ((lim - start) & ~3) + t; i < lim; i += TPB)
            atomicAdd(&lcnt[dst[i] >> BSHIFT], 1);
        __syncthreads();
        for (int j = t; j < NB; j += TPB) cntT[j * NWRITERS + hb] = lcnt[j];
        return;
    }

    // ---- gemm1 MFMA: 4 waves x 16 rows = 64 rows/block ----
    for (int i = t; i < 2048; i += TPB) {
        int k = i >> 4, cw = (i & 15) * 4;
        float4 u = reinterpret_cast<const float4*>(W1)[i];
        wT[(cw + 0) * 136 + k] = f2bf(u.x);
        wT[(cw + 1) * 136 + k] = f2bf(u.y);
        wT[(cw + 2) * 136 + k] = f2bf(u.z);
        wT[(cw + 3) * 136 + k] = f2bf(u.w);
    }
    if (t < 64) b1s[t] = b1[t];
    __syncthreads();

    const int l = t & 63, wid = t >> 6;
    const int cl = l & 15, kg = l >> 4;
    const int rw = ((int)blockIdx.x - NWRITERS) * 64 + wid * 16;
    if (rw >= N) return;
    const int r = rw + cl;

    const float4* xp4 = reinterpret_cast<const float4*>(x) + ((size_t)min(r, N - 1) * 32 + kg * 2);

    f32x4 acc[4] = {};
    #pragma unroll
    for (int kt = 0; kt < 4; ++kt) {
        float4 fA = xp4[kt * 8];
        float4 fB = xp4[kt * 8 + 1];
        short8v a;
        a[0] = (short)f2bf(fA.x); a[1] = (short)f2bf(fA.y);
        a[2] = (short)f2bf(fA.z); a[3] = (short)f2bf(fA.w);
        a[4] = (short)f2bf(fB.x); a[5] = (short)f2bf(fB.y);
        a[6] = (short)f2bf(fB.z); a[7] = (short)f2bf(fB.w);
        #pragma unroll
        for (int ct = 0; ct < 4; ++ct) {
            short8v b = *reinterpret_cast<const short8v*>(
                &wT[(ct * 16 + cl) * 136 + kt * 32 + kg * 8]);
            acc[ct] = __builtin_amdgcn_mfma_f32_16x16x32_bf16(a, b, acc[ct], 0, 0, 0);
        }
    }

    #pragma unroll
    for (int ct = 0; ct < 4; ++ct) {
        #pragma unroll
        for (int reg = 0; reg < 4; ++reg) {
            int row = rw + kg * 4 + reg;
            float v = acc[ct][reg] + b1s[ct * 16 + cl];
            unsigned int m = (unsigned int)f2bf(v);
            unsigned int p = (unsigned int)__shfl_xor((int)m, 1);
            if (!(l & 1) && row < N)
                xlb[(size_t)row * 32 + ct * 8 + (cl >> 1)] = m | (p << 16);
        }
    }
}

// ---- K2: per-bucket scan of writer counts -> segT + totals ----
__global__ __launch_bounds__(TPB) void k_colscan(
    const int* __restrict__ cntT, int* __restrict__ segT, int* __restrict__ totals, int NB)
{
    __shared__ int wsum[4];
    const int r = blockIdx.x;
    const int t = threadIdx.x;
    const int lane = t & 63, wid = t >> 6;
    int v = cntT[r * NWRITERS + t];
    int incl = v;
    for (int d = 1; d < 64; d <<= 1) {
        int n = __shfl_up(incl, d);
        if (lane >= d) incl += n;
    }
    if (lane == 63) wsum[wid] = incl;
    __syncthreads();
    int woff = 0;
    for (int w = 0; w < wid; w++) woff += wsum[w];
    int excl = woff + incl - v;
    segT[r * NWRITERS + t] = excl;
    if (t == TPB - 1) totals[r] = excl + v;
}

// ---- K3: bin edges into block-private (writer,bucket) segments ----
__global__ __launch_bounds__(TPB) void k_fillbin(
    const int* __restrict__ ei, const int* __restrict__ segT, const int* __restrict__ totals,
    unsigned int* __restrict__ recs, int E, int NB, int CH)
{
    __shared__ int lcur[1024];
    __shared__ int bbs[1024];
    __shared__ int wsum[4];
    const int blk = blockIdx.x;
    const int t = threadIdx.x;
    const int lane = t & 63, wid = t >> 6;

    // exclusive scan of totals[0..NB-1] -> bbs (4 elems/thread)
    const int b4 = t * 4;
    int v0 = (b4 + 0 < NB) ? totals[b4 + 0] : 0;
    int v1 = (b4 + 1 < NB) ? totals[b4 + 1] : 0;
    int v2 = (b4 + 2 < NB) ? totals[b4 + 2] : 0;
    int v3 = (b4 + 3 < NB) ? totals[b4 + 3] : 0;
    int tsum = v0 + v1 + v2 + v3;
    int incl = tsum;
    for (int d = 1; d < 64; d <<= 1) {
        int n = __shfl_up(incl, d);
        if (lane >= d) incl += n;
    }
    if (lane == 63) wsum[wid] = incl;
    __syncthreads();
    int woff = 0;
    for (int w = 0; w < wid; w++) woff += wsum[w];
    int texcl = woff + incl - tsum;
    if (b4 + 0 < NB) bbs[b4 + 0] = texcl;
    if (b4 + 1 < NB) bbs[b4 + 1] = texcl + v0;
    if (b4 + 2 < NB) bbs[b4 + 2] = texcl + v0 + v1;
    if (b4 + 3 < NB) bbs[b4 + 3] = texcl + v0 + v1 + v2;
    __syncthreads();

    for (int j = t; j < NB; j += TPB)
        lcur[j] = bbs[j] + segT[j * NWRITERS + blk];
    __syncthreads();

    const int start = blk * CH;
    const int lim = min(E, start + CH);
    const int* src = ei;
    const int* dst = ei + E;
    int i = start + t * 4;
    for (; i + 3 < lim; i += TPB * 4) {
        vint4 d = __builtin_nontemporal_load(reinterpret_cast<const vint4*>(dst + i));
        vint4 s = __builtin_nontemporal_load(reinterpret_cast<const vint4*>(src + i));
        int p0 = atomicAdd(&lcur[d.x >> BSHIFT], 1);
        int p1 = atomicAdd(&lcur[d.y >> BSHIFT], 1);
        int p2 = atomicAdd(&lcur[d.z >> BSHIFT], 1);
        int p3 = atomicAdd(&lcur[d.w >> BSHIFT], 1);
        recs[p0] = ((unsigned int)s.x << BSHIFT) | (unsigned int)(d.x & (BNODES-1));
        recs[p1] = ((unsigned int)s.y << BSHIFT) | (unsigned int)(d.y & (BNODES-1));
        recs[p2] = ((unsigned int)s.z << BSHIFT) | (unsigned int)(d.z & (BNODES-1));
        recs[p3] = ((unsigned int)s.w << BSHIFT) | (unsigned int)(d.w & (BNODES-1));
    }
    for (i = start + ((lim - start) & ~3) + t; i < lim; i += TPB) {
        int d = dst[i];
        int p = atomicAdd(&lcur[d >> BSHIFT], 1);
        recs[p] = ((unsigned int)src[i] << BSHIFT) | (unsigned int)(d & (BNODES-1));
    }
}

// ---- K4: per-bucket counting sort -> node-sorted esrc + global off ----
__global__ __launch_bounds__(TPB) void k_bsort(
    const unsigned int* __restrict__ recs, const int* __restrict__ totals,
    int* __restrict__ esrc, int* __restrict__ off, int N, int NB, int E)
{
    __shared__ int h[BNODES];
    __shared__ int cur[BNODES];
    __shared__ int ws2[2];
    __shared__ int red[4];

    const int r = blockIdx.x;
    const int t = threadIdx.x;
    const int lane = t & 63, w = t >> 6;

    int s = 0;
    for (int j = t; j < r; j += TPB) s += totals[j];
    #pragma unroll
    for (int d = 32; d >= 1; d >>= 1) s += __shfl_xor(s, d);
    if (lane == 0) red[w] = s;
    if (t < BNODES) h[t] = 0;
    __syncthreads();
    const int bb0 = red[0] + red[1] + red[2] + red[3];
    const int bb1 = bb0 + totals[r];

    for (int i = bb0 + t; i < bb1; i += TPB)
        atomicAdd(&h[recs[i] & (BNODES - 1)], 1);
    __syncthreads();

    int v = 0, incl = 0;
    if (t < BNODES) {
        v = h[t];
        incl = v;
        for (int d = 1; d < 64; d <<= 1) {
            int n = __shfl_up(incl, d);
            if (lane >= d) incl += n;
        }
        if (lane == 63) ws2[w] = incl;
    }
    __syncthreads();
    if (t < BNODES) {
        int excl = incl - v + (w ? ws2[0] : 0);
        cur[t] = bb0 + excl;
        int node = r * BNODES + t;
        if (node < N) off[node] = bb0 + excl;
    }
    if (r == NB - 1 && t == 0) off[N] = E;
    __syncthreads();

    for (int i = bb0 + t; i < bb1; i += TPB) {
        unsigned int rec = recs[i];
        int p = atomicAdd(&cur[rec & (BNODES - 1)], 1);
        esrc[p] = (int)(rec >> BSHIFT);
    }
}

// ---- K5: aggregate + ReLU + GEMM2 (round-12 proven: 8 slots x uint4, 8192 blocks) ----
#define AGG_BLOCKS 8192
__global__ __launch_bounds__(TPB) void k_agg(
    const unsigned int* __restrict__ xlb,  // [N,32] u32 (bf16 pairs)
    const int* __restrict__ off,           // [N+1]
    const int* __restrict__ esrc,          // [E]
    const float* __restrict__ W2,          // [64,32]
    const float* __restrict__ b2,          // [32]
    float* __restrict__ out, int N)
{
    __shared__ float w2s[64 * 32];
    __shared__ float b2s[32];
    __shared__ float arow[4][68];

    const int t = threadIdx.x;
    const float4* w4 = reinterpret_cast<const float4*>(W2);
    for (int i = t; i < 512; i += TPB) {
        float4 u = w4[i];
        int o = i * 4;
        w2s[o+0] = u.x; w2s[o+1] = u.y; w2s[o+2] = u.z; w2s[o+3] = u.w;
    }
    if (t < 32) b2s[t] = b2[t];
    __syncthreads();

    const int wid = t >> 6, lane = t & 63;
    const int slot = lane >> 3, b = lane & 7;
    const int c = lane & 31, h = lane >> 5;
    const uint4* xb4 = reinterpret_cast<const uint4*>(xlb);

    for (int node = blockIdx.x * 4 + wid; node < N; node += gridDim.x * 4) {
        const int beg = off[node], end = off[node + 1];
        float a0=0.f,a1=0.f,a2=0.f,a3=0.f,a4=0.f,a5=0.f,a6=0.f,a7=0.f;
        int e = beg + slot;
        for (; e + 8 < end; e += 16) {
            int s0 = esrc[e];
            int s1 = esrc[e + 8];
            uint4 v0 = xb4[(size_t)s0 * 8 + b];
            uint4 v1 = xb4[(size_t)s1 * 8 + b];
            a0 += bflo(v0.x); a1 += bfhi(v0.x);
            a2 += bflo(v0.y); a3 += bfhi(v0.y);
            a4 += bflo(v0.z); a5 += bfhi(v0.z);
            a6 += bflo(v0.w); a7 += bfhi(v0.w);
            a0 += bflo(v1.x); a1 += bfhi(v1.x);
            a2 += bflo(v1.y); a3 += bfhi(v1.y);
            a4 += bflo(v1.z); a5 += bfhi(v1.z);
            a6 += bflo(v1.w); a7 += bfhi(v1.w);
        }
        if (e < end) {
            int s = esrc[e];
            uint4 v = xb4[(size_t)s * 8 + b];
            a0 += bflo(v.x); a1 += bfhi(v.x);
            a2 += bflo(v.y); a3 += bfhi(v.y);
            a4 += bflo(v.z); a5 += bfhi(v.z);
            a6 += bflo(v.w); a7 += bfhi(v.w);
        }
        #pragma unroll
        for (int d = 8; d <= 32; d <<= 1) {
            a0 += __shfl_xor(a0, d); a1 += __shfl_xor(a1, d);
            a2 += __shfl_xor(a2, d); a3 += __shfl_xor(a3, d);
            a4 += __shfl_xor(a4, d); a5 += __shfl_xor(a5, d);
            a6 += __shfl_xor(a6, d); a7 += __shfl_xor(a7, d);
        }
        if (slot == 0) {
            uint4 sv = xb4[(size_t)node * 8 + b];
            float* p = &arow[wid][b * 8];
            p[0] = fmaxf(a0 + bflo(sv.x), 0.f);
            p[1] = fmaxf(a1 + bfhi(sv.x), 0.f);
            p[2] = fmaxf(a2 + bflo(sv.y), 0.f);
            p[3] = fmaxf(a3 + bfhi(sv.y), 0.f);
            p[4] = fmaxf(a4 + bflo(sv.z), 0.f);
            p[5] = fmaxf(a5 + bfhi(sv.z), 0.f);
            p[6] = fmaxf(a6 + bflo(sv.w), 0.f);
            p[7] = fmaxf(a7 + bfhi(sv.w), 0.f);
        }
        float o = 0.f;
        const float* ar = &arow[wid][h * 32];
        const float* wp = &w2s[h * 32 * 32 + c];
        #pragma unroll
        for (int kk = 0; kk < 32; kk++)
            o = fmaf(ar[kk], wp[kk * 32], o);
        o += __shfl_xor(o, 32);
        if (h == 0) out[(size_t)node * 32 + c] = o + b2s[c];
    }
}

extern "C" void kernel_launch(void* const* d_in, const int* in_sizes, int n_in,
                              void* d_out, int out_size, void* d_ws, size_t ws_size,
                              hipStream_t stream) {
    const float* x  = (const float*)d_in[0];
    const int*   ei = (const int*)d_in[1];
    const float* W1 = (const float*)d_in[2];
    const float* b1 = (const float*)d_in[3];
    const float* W2 = (const float*)d_in[4];
    const float* b2 = (const float*)d_in[5];
    float* out = (float*)d_out;

    const int N = in_sizes[0] / 128;
    const int E = in_sizes[1] / 2;
    const int NB = (N + BNODES - 1) >> BSHIFT;
    const int CH = (((E + NWRITERS - 1) / NWRITERS) + 3) & ~3;

    char* w = (char*)d_ws;
    unsigned int* xlb = (unsigned int*)w;   w += (size_t)N * 32 * 4;          // 12.8 MB
    int* cntT   = (int*)w;                  w += (size_t)NB * NWRITERS * 4;   // 800 KB
    int* segT   = (int*)w;                  w += (size_t)NB * NWRITERS * 4;   // 800 KB
    int* totals = (int*)w;                  w += ((size_t)NB * 4 + 15) & ~15ull;
    int* off    = (int*)w;                  w += ((size_t)(N + 1) * 4 + 15) & ~15ull;
    unsigned int* recs = (unsigned int*)w;  w += (size_t)E * 4;               // 6.4 MB
    int* esrc   = (int*)w;                  // 6.4 MB

    const int nbG = (N + 63) / 64;

    hipLaunchKernelGGL(k_gemm1_hist, dim3(NWRITERS + nbG), dim3(TPB), 0, stream,
                       x, W1, b1, xlb, ei, cntT, N, E, NB, CH);
    hipLaunchKernelGGL(k_colscan, dim3(NB), dim3(TPB), 0, stream, cntT, segT, totals, NB);
    hipLaunchKernelGGL(k_fillbin, dim3(NWRITERS), dim3(TPB), 0, stream,
                       ei, segT, totals, recs, E, NB, CH);
    hipLaunchKernelGGL(k_bsort, dim3(NB), dim3(TPB), 0, stream,
                       recs, totals, esrc, off, N, NB, E);
    hipLaunchKernelGGL(k_agg, dim3(AGG_BLOCKS), dim3(TPB), 0, stream,
                       xlb, off, esrc, W2, b2, out, N);
}